// Round 10
// baseline (503.181 us; speedup 1.0000x reference)
//
#include <hip/hip_runtime.h>
#include <hip/hip_fp16.h>
#include <stdint.h>

static constexpr int N_NODES = 200000;
static constexpr int N_EDGES = 6400000;
static constexpr int F_INC = 128;
static constexpr int F1 = 12;
static constexpr int F2 = 24;
static constexpr int HS1_STRIDE = 16; // halfs -> 32 B rows
static constexpr int HS2_STRIDE = 32; // halfs -> 64 B rows
static constexpr int NBUCK = (N_NODES + 255) / 256; // 782
static constexpr int NT = 13;         // source tiles of 16384 nodes (src >> 14) -> 1 MB hs2 tiles
static constexpr int KPB = 16;        // key slots per dest (13 tiles + end sentinel)
static constexpr int CHUNK = 8192;    // edges per hist/scatter block
static constexpr int NBLK = (N_EDGES + CHUNK - 1) / CHUNK; // 782
static constexpr int CSRCAP = 9216;   // LDS csr staging cap

__device__ __forceinline__ int clampN(int v) {
    return min(max(v, 0), N_NODES - 1);
}

// ---- K1: per-block bucket histogram -> hist2d[b][k] (coalesced row write) ----
__global__ __launch_bounds__(1024) void hist_pass(const int* __restrict__ col,
                                                  int* __restrict__ hist2d) {
    __shared__ int h[NBUCK];
    int t = threadIdx.x, b = blockIdx.x;
    for (int i = t; i < NBUCK; i += 1024) h[i] = 0;
    __syncthreads();
    int base4 = (b * CHUNK) >> 2;
    const int4* col4 = (const int4*)col;
#pragma unroll
    for (int it = 0; it < CHUNK / 4096; it++) {
        int q = base4 + it * 1024 + t;
        if (q < N_EDGES / 4) { // N_EDGES % 4 == 0, no straddle
            int4 c = col4[q];
            atomicAdd(&h[clampN(c.x) >> 8], 1);
            atomicAdd(&h[clampN(c.y) >> 8], 1);
            atomicAdd(&h[clampN(c.z) >> 8], 1);
            atomicAdd(&h[clampN(c.w) >> 8], 1);
        }
    }
    __syncthreads();
    for (int k = t; k < NBUCK; k += 1024)
        hist2d[(size_t)b * NBUCK + k] = h[k];
}

// ---- K2a: per-bucket exclusive prefix over blocks (in place) + bucket total ----
__global__ __launch_bounds__(256) void colscan(int* __restrict__ hist2d,
                                               int* __restrict__ bcnt) {
    __shared__ int ps[256];
    int k = blockIdx.x, t = threadIdx.x;
    int vals[4];
    int sum = 0;
#pragma unroll
    for (int j = 0; j < 4; j++) {
        int b = t * 4 + j;
        vals[j] = (b < NBLK) ? hist2d[(size_t)b * NBUCK + k] : 0;
        sum += vals[j];
    }
    ps[t] = sum;
    int mine = sum;
    for (int off = 1; off < 256; off <<= 1) {
        __syncthreads();
        int a = (t >= off) ? ps[t - off] : 0;
        __syncthreads();
        ps[t] += a;
    }
    __syncthreads();
    int excl = ps[t] - mine;
#pragma unroll
    for (int j = 0; j < 4; j++) {
        int b = t * 4 + j;
        if (b < NBLK) hist2d[(size_t)b * NBUCK + k] = excl;
        excl += vals[j];
    }
    if (t == 255) bcnt[k] = ps[255];
}

// ---- K2b: scan bucket totals -> bbase (NBUCK+1) ----
__global__ __launch_bounds__(1024) void bucket_scan(const int* __restrict__ bcnt,
                                                    int* __restrict__ bbase) {
    __shared__ int tmp[1024];
    int t = threadIdx.x;
    int v = (t < NBUCK) ? bcnt[t] : 0;
    tmp[t] = v;
    for (int off = 1; off < 1024; off <<= 1) {
        __syncthreads();
        int a = (t >= off) ? tmp[t - off] : 0;
        __syncthreads();
        tmp[t] += a;
    }
    __syncthreads();
    if (t < NBUCK) bbase[t] = tmp[t] - v;
    if (t == 0) bbase[NBUCK] = N_EDGES;
}

// ---- K3: scatter via LDS presort by bucket -> coalesced run writes ----
__global__ __launch_bounds__(1024) void scatter2(const int* __restrict__ row,
                                                 const int* __restrict__ col,
                                                 const int* __restrict__ bbase,
                                                 const int* __restrict__ hist2d,
                                                 const int* __restrict__ bcnt,
                                                 int* __restrict__ tmpArr) {
    __shared__ int scan[1024];
    __shared__ int cur[NBUCK];
    __shared__ int gbase[NBUCK];
    __shared__ int ebufA[CHUNK]; // 32 KB packed records, bucket-sorted
    __shared__ int ebufB[CHUNK]; // 32 KB global dest addresses (monotone per run)
    int t = threadIdx.x, b = blockIdx.x;
    int myBase = 0, myCnt = 0;
    if (t < NBUCK) {
        myBase = hist2d[(size_t)b * NBUCK + t];
        int nxt = (b + 1 < NBLK) ? hist2d[(size_t)(b + 1) * NBUCK + t] : bcnt[t];
        myCnt = nxt - myBase;
    }
    scan[t] = myCnt;
    for (int off = 1; off < 1024; off <<= 1) {
        __syncthreads();
        int a = (t >= off) ? scan[t - off] : 0;
        __syncthreads();
        scan[t] += a;
    }
    __syncthreads();
    if (t < NBUCK) {
        int lexcl = scan[t] - myCnt;
        cur[t] = lexcl;
        gbase[t] = bbase[t] + myBase - lexcl;
    }
    __syncthreads();
    int base4 = (b * CHUNK) >> 2;
    const int4* col4 = (const int4*)col;
    const int4* row4 = (const int4*)row;
#pragma unroll
    for (int it = 0; it < CHUNK / 4096; it++) {
        int q = base4 + it * 1024 + t;
        if (q < N_EDGES / 4) {
            int4 c4 = col4[q];
            int4 r4 = row4[q];
            int cc[4] = {c4.x, c4.y, c4.z, c4.w};
            int rr[4] = {r4.x, r4.y, r4.z, r4.w};
#pragma unroll
            for (int u = 0; u < 4; u++) {
                int c = clampN(cc[u]);
                int r = clampN(rr[u]);
                int k = c >> 8;
                int p = atomicAdd(&cur[k], 1);
                ebufA[p] = (r << 8) | (c & 255);
                ebufB[p] = gbase[k] + p;
            }
        }
    }
    __syncthreads();
    int n = min(CHUNK, N_EDGES - b * CHUNK);
    for (int i = t; i < n; i += 1024)
        tmpArr[ebufB[i]] = ebufA[i]; // consecutive i -> consecutive addr within runs
}

// ---- pass C: per-bucket counting sort by (dlocal, tile13), LDS csr staging ----
__global__ __launch_bounds__(256) void bucket_fill(const int* __restrict__ tmpArr,
                                                   const int* __restrict__ bbase,
                                                   unsigned short* __restrict__ offs2,
                                                   float* __restrict__ dinv,
                                                   int* __restrict__ csr) {
    __shared__ int hist[256 * KPB]; // 16 KB
    __shared__ int part[256];
    __shared__ int lbuf[CSRCAP];    // 36 KB csr staging
    int b = blockIdx.x, t = threadIdx.x;
    int node0 = b << 8;
    int s = bbase[b], e = bbase[b + 1];
    int cnt = e - s;
    bool fits = cnt <= CSRCAP;
    for (int k = t; k < 256 * KPB; k += 256) hist[k] = 0;
    __syncthreads();
    for (int i = s + t; i < e; i += 256) {
        int en = tmpArr[i];
        int key = ((en & 255) << 4) | ((en >> 8) >> 14);
        atomicAdd(&hist[key], 1);
    }
    __syncthreads();
    // thread t == dest t: serial exclusive scan of its 16 key slots
    int base = t << 4;
    int ex[KPB];
    int sum = 0;
#pragma unroll
    for (int j = 0; j < KPB; j++) { ex[j] = sum; sum += hist[base + j]; }
    part[t] = sum;
    int nn = min(256, N_NODES - node0);
    if (t < nn) dinv[node0 + t] = rsqrtf((float)(sum + 1));
    // block exclusive scan over part
    int mine = sum;
    for (int off = 1; off < 256; off <<= 1) {
        __syncthreads();
        int a = (t >= off) ? part[t - off] : 0;
        __syncthreads();
        part[t] += a;
    }
    __syncthreads();
    int chunk0 = part[t] - mine; // exclusive prefix for this dest
#pragma unroll
    for (int j = 0; j < KPB; j++) hist[base + j] = chunk0 + ex[j];
    __syncthreads();
    // offs2: bucket-local u16 starts; slot 13 = dest end (slots 13..15 zero-count)
    for (int k = t; k < 256 * KPB; k += 256)
        offs2[((size_t)b << 12) + k] = (unsigned short)hist[k];
    __syncthreads();
    // scatter into LDS window (coalesced stream-out), fallback to global if oversized
    for (int i = s + t; i < e; i += 256) {
        int en = tmpArr[i];
        int src = en >> 8;
        int key = ((en & 255) << 4) | (src >> 14);
        int p = atomicAdd(&hist[key], 1);
        if (fits) lbuf[p] = src; else csr[s + p] = src;
    }
    __syncthreads();
    if (fits)
        for (int i = t; i < cnt; i += 256) csr[s + i] = lbuf[i];
}

// ---- hs1[v] = (x[v] @ W1) * dinv[v], fp16, 32 B rows ----
__global__ __launch_bounds__(256) void gemm1(const float* __restrict__ x,
                                             const float* __restrict__ W1,
                                             const float* __restrict__ dinv,
                                             __half* __restrict__ hs1) {
    __shared__ float Wl[F_INC * F1];
    for (int i = threadIdx.x; i < F_INC * F1; i += 256) Wl[i] = W1[i];
    __syncthreads();
    int v = blockIdx.x * 256 + threadIdx.x;
    if (v >= N_NODES) return;
    float acc[F1];
#pragma unroll
    for (int f = 0; f < F1; f++) acc[f] = 0.f;
    const float4* xr = (const float4*)(x + (size_t)v * F_INC);
    for (int k4 = 0; k4 < F_INC / 4; k4++) {
        float4 xv = xr[k4];
        int kb = k4 * 4;
#pragma unroll
        for (int f = 0; f < F1; f++) {
            acc[f] += xv.x * Wl[(kb + 0) * F1 + f] + xv.y * Wl[(kb + 1) * F1 + f] +
                      xv.z * Wl[(kb + 2) * F1 + f] + xv.w * Wl[(kb + 3) * F1 + f];
        }
    }
    float dv = dinv[v];
    int w[6];
#pragma unroll
    for (int j = 0; j < 6; j++) {
        __half2 p = __floats2half2_rn(acc[2 * j] * dv, acc[2 * j + 1] * dv);
        w[j] = *(int*)&p;
    }
    __half* rowp = hs1 + (size_t)v * HS1_STRIDE;
    ((int4*)rowp)[0] = make_int4(w[0], w[1], w[2], w[3]);
    ((int2*)rowp)[2] = make_int2(w[4], w[5]);
}

__device__ __forceinline__ void acc_row1(float* acc, const __half* rowp) {
    int4 a = ((const int4*)rowp)[0];
    int2 b = ((const int2*)rowp)[2];
    int ws[6] = {a.x, a.y, a.z, a.w, b.x, b.y};
#pragma unroll
    for (int j = 0; j < 6; j++) {
        float2 t = __half22float2(*(__half2*)&ws[j]);
        acc[2 * j] += t.x;
        acc[2 * j + 1] += t.y;
    }
}

__device__ __forceinline__ void acc_row2(float* acc, const __half* rowp) {
    int4 a = ((const int4*)rowp)[0];
    int4 b = ((const int4*)rowp)[1];
    int4 c = ((const int4*)rowp)[2];
    int ws[12] = {a.x, a.y, a.z, a.w, b.x, b.y, b.z, b.w, c.x, c.y, c.z, c.w};
#pragma unroll
    for (int j = 0; j < 12; j++) {
        float2 t = __half22float2(*(__half2*)&ws[j]);
        acc[2 * j] += t.x;
        acc[2 * j + 1] += t.y;
    }
}

__device__ __forceinline__ void unpack14(int* of, const unsigned short* offs2,
                                         int b, int t) {
    const int4* p = (const int4*)(offs2 + (((size_t)b << 12) + ((size_t)t << 4)));
    int4 q0 = p[0], q1 = p[1];
    of[0] = q0.x & 0xffff;  of[1] = (q0.x >> 16) & 0xffff;
    of[2] = q0.y & 0xffff;  of[3] = (q0.y >> 16) & 0xffff;
    of[4] = q0.z & 0xffff;  of[5] = (q0.z >> 16) & 0xffff;
    of[6] = q0.w & 0xffff;  of[7] = (q0.w >> 16) & 0xffff;
    of[8] = q1.x & 0xffff;  of[9] = (q1.x >> 16) & 0xffff;
    of[10] = q1.y & 0xffff; of[11] = (q1.y >> 16) & 0xffff;
    of[12] = q1.z & 0xffff; of[13] = (q1.z >> 16) & 0xffff;
}

// ---- layer-1 aggregate: per-tile WAVE-LOCKED walk (exec-mask sync, no barrier).
//      All lanes of a wave gather from the same 0.5 MB hs1 tile -> L2-resident. ----
__global__ __launch_bounds__(256, 4) void agg1(const __half* __restrict__ hs1,
                                               const unsigned short* __restrict__ offs2,
                                               const int* __restrict__ csr,
                                               const int* __restrict__ bbase,
                                               const float* __restrict__ dinv,
                                               const float* __restrict__ W2,
                                               const float* __restrict__ b1,
                                               __half* __restrict__ hs2) {
    __shared__ float Wl[F1 * F2];
    __shared__ float bl[F1];
    int t = threadIdx.x, b = blockIdx.x;
    for (int i = t; i < F1 * F2; i += 256) Wl[i] = W2[i];
    if (t < F1) bl[t] = b1[t];
    __syncthreads();
    int v = (b << 8) + t;
    bool valid = v < N_NODES;
    int bb = bbase[b];
    float acc[F1];
#pragma unroll
    for (int f = 0; f < F1; f++) acc[f] = 0.f;
    if (valid) acc_row1(acc, hs1 + (size_t)v * HS1_STRIDE); // self loop
    int of[14];
    unpack14(of, offs2, b, t);
    for (int tl = 0; tl < NT; tl++) {
        int i = bb + of[tl], e = bb + of[tl + 1];
        for (; i < e; ++i) // divergent; wave stays within tile tl (exec-mask lockstep)
            acc_row1(acc, hs1 + (size_t)csr[i] * HS1_STRIDE);
    }
    if (!valid) return;
    float dv = dinv[v];
    float o[F1];
#pragma unroll
    for (int f = 0; f < F1; f++) o[f] = fmaxf(dv * acc[f] + bl[f], 0.f);
    float h2[F2];
#pragma unroll
    for (int g = 0; g < F2; g++) {
        float sum = 0.f;
#pragma unroll
        for (int f = 0; f < F1; f++) sum += o[f] * Wl[f * F2 + g];
        h2[g] = dv * sum;
    }
    int w[12];
#pragma unroll
    for (int j = 0; j < 12; j++) {
        __half2 p = __floats2half2_rn(h2[2 * j], h2[2 * j + 1]);
        w[j] = *(int*)&p;
    }
    int4* op = (int4*)(hs2 + (size_t)v * HS2_STRIDE);
    op[0] = make_int4(w[0], w[1], w[2], w[3]);
    op[1] = make_int4(w[4], w[5], w[6], w[7]);
    op[2] = make_int4(w[8], w[9], w[10], w[11]);
}

// ---- layer-2 aggregate: per-tile wave-locked walk + relu + fc1(relu) + fc2 ----
__global__ __launch_bounds__(256, 4) void agg2(const __half* __restrict__ hs2,
                                               const unsigned short* __restrict__ offs2,
                                               const int* __restrict__ csr,
                                               const int* __restrict__ bbase,
                                               const float* __restrict__ dinv,
                                               const float* __restrict__ b2,
                                               const float* __restrict__ Wf1,
                                               const float* __restrict__ bf1,
                                               const float* __restrict__ Wf2,
                                               const float* __restrict__ bf2,
                                               float* __restrict__ out) {
    __shared__ float W1s[F2 * 32];
    __shared__ float W2s[32 * 2];
    __shared__ float b2s[F2], b1s[32], bfs[2];
    int t = threadIdx.x, b = blockIdx.x;
    for (int i = t; i < F2 * 32; i += 256) W1s[i] = Wf1[i];
    if (t < 64) W2s[t] = Wf2[t];
    if (t < F2) b2s[t] = b2[t];
    if (t < 32) b1s[t] = bf1[t];
    if (t < 2) bfs[t] = bf2[t];
    __syncthreads();
    int v = (b << 8) + t;
    bool valid = v < N_NODES;
    int bb = bbase[b];
    float acc[F2];
#pragma unroll
    for (int f = 0; f < F2; f++) acc[f] = 0.f;
    if (valid) acc_row2(acc, hs2 + (size_t)v * HS2_STRIDE); // self loop
    int of[14];
    unpack14(of, offs2, b, t);
    for (int tl = 0; tl < NT; tl++) {
        int i = bb + of[tl], e = bb + of[tl + 1];
        for (; i < e; ++i) // divergent; wave stays within 1 MB hs2 tile
            acc_row2(acc, hs2 + (size_t)csr[i] * HS2_STRIDE);
    }
    if (!valid) return;
    float dv = dinv[v];
    float o2[F2];
#pragma unroll
    for (int f = 0; f < F2; f++) o2[f] = fmaxf(dv * acc[f] + b2s[f], 0.f);
    float c0 = bfs[0], c1 = bfs[1];
#pragma unroll
    for (int g = 0; g < 32; g++) {
        float sum = b1s[g];
#pragma unroll
        for (int f = 0; f < F2; f++) sum += o2[f] * W1s[f * 32 + g];
        sum = fmaxf(sum, 0.f);
        c0 += sum * W2s[2 * g + 0];
        c1 += sum * W2s[2 * g + 1];
    }
    float2 r; r.x = c0; r.y = c1;
    ((float2*)out)[v] = r;
}

extern "C" void kernel_launch(void* const* d_in, const int* in_sizes, int n_in,
                              void* d_out, int out_size, void* d_ws, size_t ws_size,
                              hipStream_t stream) {
    const float* x = (const float*)d_in[0];
    const int* erow = (const int*)d_in[1]; // edge_index delivered as int32
    const int* ecol = erow + N_EDGES;
    const float* W1 = (const float*)d_in[2];
    const float* b1 = (const float*)d_in[3];
    const float* W2 = (const float*)d_in[4];
    const float* b2 = (const float*)d_in[5];
    const float* Wf1 = (const float*)d_in[6];
    const float* bf1 = (const float*)d_in[7];
    const float* Wf2 = (const float*)d_in[8];
    const float* bf2 = (const float*)d_in[9];
    float* out = (float*)d_out;

    char* w = (char*)d_ws;
    auto alloc = [&](size_t bytes) -> char* {
        char* p = w;
        w += (bytes + 255) / 256 * 256;
        return p;
    };
    int* bcnt = (int*)alloc((size_t)NBUCK * 4);
    int* bbase = (int*)alloc((size_t)(NBUCK + 1) * 4);
    int* hist2d = (int*)alloc((size_t)NBLK * NBUCK * 4); // 2.45 MB
    float* dinv = (float*)alloc((size_t)N_NODES * 4);
    unsigned short* offs2 = (unsigned short*)alloc((size_t)NBUCK * 256 * KPB * 2 + 256); // 6.4 MB (+pad)
    int* csr = (int*)alloc((size_t)N_EDGES * 4); // 25.6 MB
    // union: tmpArr (25.6 MB) dead after bucket_fill; hs1 (6.4) + hs2 (12.8) after
    size_t hs1_bytes = (size_t)N_NODES * HS1_STRIDE * 2;
    char* uni = alloc((size_t)N_EDGES * 4);
    int* tmpArr = (int*)uni;
    __half* hs1 = (__half*)uni;
    __half* hs2 = (__half*)(uni + hs1_bytes);

    const int nodeGrid = (N_NODES + 255) / 256;

    hipLaunchKernelGGL(hist_pass, dim3(NBLK), dim3(1024), 0, stream, ecol, hist2d);
    hipLaunchKernelGGL(colscan, dim3(NBUCK), dim3(256), 0, stream, hist2d, bcnt);
    hipLaunchKernelGGL(bucket_scan, dim3(1), dim3(1024), 0, stream, bcnt, bbase);
    hipLaunchKernelGGL(scatter2, dim3(NBLK), dim3(1024), 0, stream, erow, ecol, bbase, hist2d, bcnt, tmpArr);
    hipLaunchKernelGGL(bucket_fill, dim3(NBUCK), dim3(256), 0, stream, tmpArr, bbase, offs2, dinv, csr);
    hipLaunchKernelGGL(gemm1, dim3(nodeGrid), dim3(256), 0, stream, x, W1, dinv, hs1);
    hipLaunchKernelGGL(agg1, dim3(NBUCK), dim3(256), 0, stream,
                       hs1, offs2, csr, bbase, dinv, W2, b1, hs2);
    hipLaunchKernelGGL(agg2, dim3(NBUCK), dim3(256), 0, stream,
                       hs2, offs2, csr, bbase, dinv, b2, Wf1, bf1, Wf2, bf2, out);
}